// Round 7
// baseline (843.882 us; speedup 1.0000x reference)
//
#include <hip/hip_runtime.h>
#include <hip/hip_bf16.h>
#include <math.h>

#define GLB __attribute__((address_space(1)))
#define LDSAS __attribute__((address_space(3)))

typedef __attribute__((ext_vector_type(8))) short short8;
typedef __attribute__((ext_vector_type(4))) float floatx4;
typedef unsigned short u16;

// ---------- scalar helpers ----------
// Compiler-native bf16 convert (m240: scalar cast is the fast path; adjacent
// converts pack into v_cvt_pk_bf16_f32).
static __device__ __forceinline__ u16 f2bf(float f) {
  __hip_bfloat16 h = __float2bfloat16(f);
  return __builtin_bit_cast(u16, h);
}
static __device__ __forceinline__ float bf2f(u16 h) {
  return __bfloat162float(__builtin_bit_cast(__hip_bfloat16, h));
}
static __device__ __forceinline__ float tanh_fast(float x) {
  float e = __expf(2.0f * x);
  return 1.0f - 2.0f / (e + 1.0f);       // exact at +-inf overflow: ->1 / ->-1
}
static __device__ __forceinline__ floatx4 mfma16(short8 a, short8 b, floatx4 c) {
  return __builtin_amdgcn_mfma_f32_16x16x32_bf16(a, b, c, 0, 0, 0);
}

// ---------- LDS staging with chunk-XOR swizzle ----------
// Tile [R rows][CPR 16B-chunks per row] bf16, CPR = 1<<L2CPR, row stride ld
// elems. LDS linear slot (r,c) receives global chunk (r, c^(r&7)); reads undo
// the XOR. global_load_lds writes linearly (wave-uniform base + lane*16), so
// the per-lane GLOBAL source address carries the swizzle (rule #21).
template <int NCHUNK, int NTHREADS, int L2CPR>
static __device__ __forceinline__ void stage_swz(const u16* __restrict__ g, int ld,
                                                 u16* lds_base, int tid) {
#pragma unroll
  for (int s0 = 0; s0 < NCHUNK; s0 += NTHREADS) {
    int s = s0 + tid;
    int r = s >> L2CPR, c = s & ((1 << L2CPR) - 1);
    const u16* src = g + r * ld + ((c ^ (r & 7)) << 3);
    __builtin_amdgcn_global_load_lds((const GLB unsigned int*)src,
                                     (LDSAS unsigned int*)(lds_base + ((unsigned)(s0 + (tid & ~63)) << 3)),
                                     16, 0, 0);
  }
}

static __device__ __forceinline__ short8 frag_swz(const u16* tile, int row, int kc) {
  return *(const short8*)(tile + row * 64 + ((kc ^ (row & 7)) << 3));
}

// ---------- prep ----------
// W1x_t[n][k]: bf16 transposed (phase A stages it through LDS).
// W1h_p / W2_p: packed MFMA B-fragments. frag f = kc*32+nf (kc 0..15 = 32-wide
// k-chunk, nf 0..31 = 16-wide n-chunk); lane l holds n = nf*16+(l&15),
// k = kc*32+(l>>4)*8 .. +8 — 1KB/frag, lane-linear 16B loads.
__global__ __launch_bounds__(256) void k_prep(const float* __restrict__ W1, const float* __restrict__ W2,
                                              u16* __restrict__ W1x_t, u16* __restrict__ W1h_p,
                                              u16* __restrict__ W2_p) {
  int id = blockIdx.x * 256 + threadIdx.x;   // 98304
  int m = id >> 15;
  int r = id & 32767;
  if (m == 0) {
    int n = r >> 6, c = r & 63;
    const float* src = W1 + n;
    short8 pk;
#pragma unroll
    for (int j = 0; j < 8; ++j) pk[j] = (short)f2bf(src[(size_t)(c * 8 + j) * 512]);
    *(short8*)(W1x_t + (size_t)n * 512 + c * 8) = pk;
  } else {
    int f = r >> 6, l = r & 63;
    int kc = f >> 5, nf = f & 31;
    int n = (nf << 4) + (l & 15);
    int kb = (kc << 5) + ((l >> 4) << 3);
    const float* src = (m == 1) ? (W1 + (size_t)512 * 512) : W2;
    u16* dst = (m == 1) ? W1h_p : W2_p;
    short8 pk;
#pragma unroll
    for (int e = 0; e < 8; ++e) pk[e] = (short)f2bf(src[(size_t)(kb + e) * 512 + n]);
    *(short8*)(dst + ((size_t)f << 9) + (l << 3)) = pk;
  }
}

// ---------- Phase A: U = bf16(x @ W1x + b1)   (M=65536, N=512, K=512) ----------
__global__ __launch_bounds__(256, 2) void k_phaseA(const float* __restrict__ X,
                                                   const u16* __restrict__ Bt,
                                                   const float* __restrict__ b1,
                                                   u16* __restrict__ Ub) {
  int flat = blockIdx.x;
  int v = ((flat & 7) << 8) + (flat >> 3);   // XCD-chunked, bijective (2048 % 8 == 0)
  const int mt = v >> 2, nt = v & 3;
  const int tid = threadIdx.x;
  const int lane = tid & 63, wv = tid >> 6;
  const int wm = wv >> 1, wn = wv & 1;
  const int l15 = lane & 15, lg = lane >> 4;
  __shared__ __align__(16) u16 As[128 * 64];
  __shared__ __align__(16) u16 Bs[128 * 64];
  floatx4 acc[4][4];
  const floatx4 z4 = {0.f, 0.f, 0.f, 0.f};
#pragma unroll
  for (int i = 0; i < 4; ++i)
#pragma unroll
    for (int j = 0; j < 4; ++j) acc[i][j] = z4;

  const float* Ab = X + (size_t)(mt * 128) * 512;
  const u16* Bb = Bt + (size_t)(nt * 128) * 512;

  for (int kt = 0; kt < 8; ++kt) {
    // A: inline f32->bf16 convert into swizzled LDS slots
#pragma unroll
    for (int s0 = 0; s0 < 1024; s0 += 256) {
      int s = s0 + tid;
      int r = s >> 3, c = s & 7;
      const float* sp = Ab + (size_t)r * 512 + kt * 64 + c * 8;
      float4 f0 = *(const float4*)sp;
      float4 f1 = *(const float4*)(sp + 4);
      short8 pk;
      pk[0] = (short)f2bf(f0.x); pk[1] = (short)f2bf(f0.y);
      pk[2] = (short)f2bf(f0.z); pk[3] = (short)f2bf(f0.w);
      pk[4] = (short)f2bf(f1.x); pk[5] = (short)f2bf(f1.y);
      pk[6] = (short)f2bf(f1.z); pk[7] = (short)f2bf(f1.w);
      *(short8*)(As + r * 64 + ((c ^ (r & 7)) << 3)) = pk;
    }
    stage_swz<1024, 256, 3>(Bb + kt * 64, 512, Bs, tid);
    __syncthreads();
#pragma unroll
    for (int ks = 0; ks < 2; ++ks) {
      int kc = ks * 4 + lg;
      short8 a[4], b[4];
#pragma unroll
      for (int i = 0; i < 4; ++i) a[i] = frag_swz(As, wm * 64 + i * 16 + l15, kc);
#pragma unroll
      for (int i = 0; i < 4; ++i) b[i] = frag_swz(Bs, wn * 64 + i * 16 + l15, kc);
#pragma unroll
      for (int mi = 0; mi < 4; ++mi)
#pragma unroll
        for (int ni = 0; ni < 4; ++ni) acc[mi][ni] = mfma16(a[mi], b[ni], acc[mi][ni]);
    }
    __syncthreads();
  }
  const int r0 = mt * 128 + wm * 64, c0 = nt * 128 + wn * 64;
#pragma unroll
  for (int ni = 0; ni < 4; ++ni) {
    int col = c0 + ni * 16 + l15;
    float bb = b1[col];
#pragma unroll
    for (int mi = 0; mi < 4; ++mi)
#pragma unroll
      for (int j = 0; j < 4; ++j) {
        int row = r0 + mi * 16 + lg * 4 + j;
        Ub[(size_t)row * 512 + col] = f2bf(acc[mi][ni][j] + bb);
      }
  }
}

// ---------- Phase B: whole 32-step recurrence in ONE kernel ----------
// 128 blocks x 16 rows; state lives in LDS (chunk-XOR swizzled) for all steps.
// W1h kc=0..8 PERSISTS in registers across the t-loop (144 VGPR/lane, loaded
// once); kc=9..15 streamed from L2 via 2-deep static rotation (all indices
// compile-time -> registers, rule #20). U_t staged to LDS by global_load_lds
// ([16][512] wide mapping), hidden under the K-loop, consumed post-barrier.
__global__ __launch_bounds__(512, 2) void k_stepseq(const float* __restrict__ pre,
                                                    const u16* __restrict__ Ub,
                                                    const u16* __restrict__ W1h_p,
                                                    u16* __restrict__ H,
                                                    float* __restrict__ Fs) {
  const int mt = blockIdx.x;          // 128 blocks x 16 rows
  const int r0 = mt * 16;
  const int tid = threadIdx.x;
  const int lane = tid & 63, wn = tid >> 6;      // 8 waves, wave tile 16m x 64n
  const int l15 = lane & 15, lg = lane >> 4;
  __shared__ __align__(16) u16 Ah[16 * 512];     // state, swizzled chunks
  __shared__ __align__(16) u16 Us[16 * 512];     // U_t tile, swizzled chunks

  // stage pre_state -> Ah (f32 load, bf16 convert, swizzled write)
  const float* Sp = pre + ((size_t)r0 << 9);
#pragma unroll
  for (int s0 = 0; s0 < 1024; s0 += 512) {
    int s = s0 + tid;
    int r = s >> 6, c = s & 63;
    const float* sp = Sp + ((size_t)r << 9) + (c << 3);
    float4 f0 = *(const float4*)sp;
    float4 f1 = *(const float4*)(sp + 4);
    short8 pk;
    pk[0] = (short)f2bf(f0.x); pk[1] = (short)f2bf(f0.y);
    pk[2] = (short)f2bf(f0.z); pk[3] = (short)f2bf(f0.w);
    pk[4] = (short)f2bf(f1.x); pk[5] = (short)f2bf(f1.y);
    pk[6] = (short)f2bf(f1.z); pk[7] = (short)f2bf(f1.w);
    *(short8*)(Ah + (r << 9) + ((c ^ (r & 7)) << 3)) = pk;
  }

  // persistent 9/16 of W1h: frag f = kc*32 + wn*4 + i, this lane's 16B
  const u16* Wb = W1h_p + ((size_t)(wn * 4) << 9) + (lane << 3);
  short8 breg[9][4];
#pragma unroll
  for (int kc = 0; kc < 9; ++kc)
#pragma unroll
    for (int i = 0; i < 4; ++i)
      breg[kc][i] = *(const short8*)(Wb + ((size_t)(kc * 32 + i) << 9));

  __syncthreads();
  const floatx4 z4 = {0.f, 0.f, 0.f, 0.f};

  for (int t = 0; t < 32; ++t) {
    // U_t -> LDS ([16][512] tile, 64 chunks/row; completes by the barrier)
    stage_swz<1024, 512, 6>(Ub + ((size_t)t << 20) + ((size_t)r0 << 9), 512, Us, tid);

    // streamed 7/16 prefetch, 2-deep rotation (groups 9..15)
    short8 sb[2][4];
#pragma unroll
    for (int d = 0; d < 2; ++d)
#pragma unroll
      for (int i = 0; i < 4; ++i)
        sb[d][i] = *(const short8*)(Wb + ((size_t)((9 + d) * 32 + i) << 9));

    floatx4 acc[4] = {z4, z4, z4, z4};
#pragma unroll
    for (int kc = 0; kc < 16; ++kc) {
      short8 c0, c1, c2, c3;
      if (kc < 9) {
        c0 = breg[kc][0]; c1 = breg[kc][1]; c2 = breg[kc][2]; c3 = breg[kc][3];
      } else {
        const int d = (kc - 9) & 1;
        c0 = sb[d][0]; c1 = sb[d][1]; c2 = sb[d][2]; c3 = sb[d][3];
        if (kc + 2 < 16) {
#pragma unroll
          for (int i = 0; i < 4; ++i)
            sb[d][i] = *(const short8*)(Wb + ((size_t)((kc + 2) * 32 + i) << 9));
        }
      }
      short8 a = *(const short8*)(Ah + (l15 << 9) + ((((kc << 2) + lg) ^ (l15 & 7)) << 3));
      __builtin_amdgcn_s_setprio(1);
      acc[0] = mfma16(a, c0, acc[0]);
      acc[1] = mfma16(a, c1, acc[1]);
      acc[2] = mfma16(a, c2, acc[2]);
      acc[3] = mfma16(a, c3, acc[3]);
      __builtin_amdgcn_s_setprio(0);
    }
    __syncthreads();   // A-reads done before state overwrite; U stage complete

    u16* Ht = H + ((size_t)t << 20) + ((size_t)r0 << 9);
#pragma unroll
    for (int ni = 0; ni < 4; ++ni)
#pragma unroll
      for (int j = 0; j < 4; ++j) {
        int row = lg * 4 + j;
        int col = wn * 64 + ni * 16 + l15;
        int ch = col >> 3;
        float uvv = bf2f(Us[(row << 9) + ((ch ^ (row & 7)) << 3) + (col & 7)]);
        float hv = tanh_fast(acc[ni][j] + uvv);
        u16 hb = f2bf(hv);
        Ht[(size_t)row * 512 + col] = hb;
        if (t == 31) Fs[(size_t)(r0 + row) * 512 + col] = hv;
        Ah[(row << 9) + ((ch ^ (row & 7)) << 3) + (col & 7)] = hb;
      }
    __syncthreads();
  }
}

// ---------- Phase C: out = softmax(H @ W2 + b2)  (M=65536, full N=512/block) ----------
// B-operand straight from packed W2_p frags (register path, no LDS staging —
// stepseq's pattern); only H goes through LDS. Online single-barrier softmax:
// per-wave (m_w, s_w), combine via s_w*exp(m_w-M) after ONE barrier.
__global__ __launch_bounds__(512, 2) void k_phaseC(const u16* __restrict__ H,
                                                   const u16* __restrict__ W2_p,
                                                   const float* __restrict__ b2,
                                                   float* __restrict__ Out) {
  int bt = ((blockIdx.x & 7) << 7) + (blockIdx.x >> 3);   // XCD-chunked (1024 % 8 == 0)
  const int tid = threadIdx.x, lane = tid & 63, wv = tid >> 6;
  const int wm = wv >> 2, wn = wv & 3;
  const int l15 = lane & 15, lg = lane >> 4;
  __shared__ __align__(16) u16 As[64 * 64];
  __shared__ float redmax[4][64];
  __shared__ float redsum[4][64];
  const floatx4 z4 = {0.f, 0.f, 0.f, 0.f};
  floatx4 acc[2][8];
#pragma unroll
  for (int i = 0; i < 2; ++i)
#pragma unroll
    for (int j = 0; j < 8; ++j) acc[i][j] = z4;

  const u16* Ab = H + (size_t)(bt * 64) * 512;
  const u16* Wb = W2_p + ((size_t)(wn * 8) << 9) + (lane << 3);  // nf base = wn*8

  for (int kt = 0; kt < 8; ++kt) {
    stage_swz<512, 512, 3>(Ab + kt * 64, 512, As, tid);
    __syncthreads();
#pragma unroll
    for (int ks = 0; ks < 2; ++ks) {
      int kc = ks * 4 + lg;          // LDS 8-elem chunk index for A
      int kcg = kt * 2 + ks;         // global 32-wide k-chunk for B frags
      short8 a[2], b[8];
#pragma unroll
      for (int i = 0; i < 2; ++i) a[i] = frag_swz(As, wm * 32 + i * 16 + l15, kc);
#pragma unroll
      for (int i = 0; i < 8; ++i) b[i] = *(const short8*)(Wb + ((size_t)(kcg * 32 + i) << 9));
#pragma unroll
      for (int mi = 0; mi < 2; ++mi)
#pragma unroll
        for (int ni = 0; ni < 8; ++ni) acc[mi][ni] = mfma16(a[mi], b[ni], acc[mi][ni]);
    }
    __syncthreads();
  }
  // logits = acc + b2; per-wave online softmax stats
  float v[2][8][4];
#pragma unroll
  for (int ni = 0; ni < 8; ++ni) {
    float bb = b2[wn * 128 + ni * 16 + l15];
#pragma unroll
    for (int mi = 0; mi < 2; ++mi)
#pragma unroll
      for (int j = 0; j < 4; ++j) v[mi][ni][j] = acc[mi][ni][j] + bb;
  }
  float mw[2][4];
#pragma unroll
  for (int mi = 0; mi < 2; ++mi)
#pragma unroll
    for (int j = 0; j < 4; ++j) {
      float m = v[mi][0][j];
#pragma unroll
      for (int ni = 1; ni < 8; ++ni) m = fmaxf(m, v[mi][ni][j]);
#pragma unroll
      for (int d = 1; d < 16; d <<= 1) m = fmaxf(m, __shfl_xor(m, d, 64));
      mw[mi][j] = m;
      float s = 0.f;
#pragma unroll
      for (int ni = 0; ni < 8; ++ni) {
        v[mi][ni][j] = __expf(v[mi][ni][j] - m);   // p = exp(v - m_w)
        s += v[mi][ni][j];
      }
#pragma unroll
      for (int d = 1; d < 16; d <<= 1) s += __shfl_xor(s, d, 64);
      if (l15 == 0) {
        int row = wm * 32 + mi * 16 + lg * 4 + j;
        redmax[wn][row] = m;
        redsum[wn][row] = s;
      }
    }
  __syncthreads();
#pragma unroll
  for (int mi = 0; mi < 2; ++mi)
#pragma unroll
    for (int j = 0; j < 4; ++j) {
      int row = wm * 32 + mi * 16 + lg * 4 + j;
      float m0 = redmax[0][row], m1 = redmax[1][row], m2 = redmax[2][row], m3 = redmax[3][row];
      float M = fmaxf(fmaxf(m0, m1), fmaxf(m2, m3));
      float S = redsum[0][row] * __expf(m0 - M) + redsum[1][row] * __expf(m1 - M) +
                redsum[2][row] * __expf(m2 - M) + redsum[3][row] * __expf(m3 - M);
      float scale = __expf(mw[mi][j] - M) / S;
#pragma unroll
      for (int ni = 0; ni < 8; ++ni)
        Out[(size_t)(bt * 64 + row) * 512 + wn * 128 + ni * 16 + l15] = v[mi][ni][j] * scale;
    }
}

// ---------- host ----------
extern "C" void kernel_launch(void* const* d_in, const int* in_sizes, int n_in,
                              void* d_out, int out_size, void* d_ws, size_t ws_size,
                              hipStream_t stream) {
  const float* input = (const float*)d_in[0];       // (32, 2048, 512)
  const float* pre_state = (const float*)d_in[1];   // (2048, 512)
  const float* W1 = (const float*)d_in[2];          // (1024, 512)
  const float* b1 = (const float*)d_in[3];          // (512,)
  const float* W2 = (const float*)d_in[4];          // (512, 512)
  const float* b2 = (const float*)d_in[5];          // (512,)

  float* out = (float*)d_out;                        // probs (32*2048*512) then final_state
  float* final_state = out + (size_t)32 * 2048 * 512;
  u16* Ub = (u16*)d_out;                             // U (bf16) aliases out; dead before phase C writes

  u16* ws16 = (u16*)d_ws;                            // total ws use: ~66 MB
  u16* W1x_t = ws16;                                 // [512][512] bf16
  u16* W1h_p = W1x_t + 262144;                       // packed frags, 512 KB
  u16* W2_p  = W1h_p + 262144;                       // packed frags, 512 KB
  u16* H     = W2_p + 262144;                        // [32][2048][512] bf16, 64 MB

  k_prep<<<384, 256, 0, stream>>>(W1, W2, W1x_t, W1h_p, W2_p);
  k_phaseA<<<2048, 256, 0, stream>>>(input, W1x_t, b1, Ub);
  k_stepseq<<<128, 512, 0, stream>>>(pre_state, Ub, W1h_p, H, final_state);
  k_phaseC<<<1024, 512, 0, stream>>>(H, W2_p, b2, out);
}

// Round 10
// 707.599 us; speedup vs baseline: 1.1926x; 1.1926x over previous
//
#include <hip/hip_runtime.h>
#include <hip/hip_bf16.h>
#include <math.h>

#define GLB __attribute__((address_space(1)))
#define LDSAS __attribute__((address_space(3)))

typedef __attribute__((ext_vector_type(8))) short short8;
typedef __attribute__((ext_vector_type(4))) float floatx4;
typedef unsigned short u16;

// ---------- scalar helpers ----------
static __device__ __forceinline__ u16 f2bf(float f) {
  __hip_bfloat16 h = __float2bfloat16(f);
  return __builtin_bit_cast(u16, h);
}
static __device__ __forceinline__ float bf2f(u16 h) {
  return __bfloat162float(__builtin_bit_cast(__hip_bfloat16, h));
}
static __device__ __forceinline__ float tanh_fast(float x) {
  float e = __expf(2.0f * x);
  return 1.0f - 2.0f / (e + 1.0f);       // exact at +-inf overflow: ->1 / ->-1
}
static __device__ __forceinline__ floatx4 mfma16(short8 a, short8 b, floatx4 c) {
  return __builtin_amdgcn_mfma_f32_16x16x32_bf16(a, b, c, 0, 0, 0);
}

// ---------- LDS staging with chunk-XOR swizzle ----------
// Tile [R rows][CPR 16B-chunks per row] bf16, CPR = 1<<L2CPR, row stride ld
// elems. LDS linear slot (r,c) receives global chunk (r, c^(r&7)); reads undo
// the XOR. global_load_lds writes linearly (wave-uniform base + lane*16), so
// the per-lane GLOBAL source address carries the swizzle (rule #21).
template <int NCHUNK, int NTHREADS, int L2CPR>
static __device__ __forceinline__ void stage_swz(const u16* __restrict__ g, int ld,
                                                 u16* lds_base, int tid) {
#pragma unroll
  for (int s0 = 0; s0 < NCHUNK; s0 += NTHREADS) {
    int s = s0 + tid;
    int r = s >> L2CPR, c = s & ((1 << L2CPR) - 1);
    const u16* src = g + r * ld + ((c ^ (r & 7)) << 3);
    __builtin_amdgcn_global_load_lds((const GLB unsigned int*)src,
                                     (LDSAS unsigned int*)(lds_base + ((unsigned)(s0 + (tid & ~63)) << 3)),
                                     16, 0, 0);
  }
}

static __device__ __forceinline__ short8 frag_swz(const u16* tile, int row, int kc) {
  return *(const short8*)(tile + row * 64 + ((kc ^ (row & 7)) << 3));
}

// ---------- prep ----------
// W1x_t[n][k]: bf16 transposed (phase A stages it through LDS).
// W1h_p / W2_p: packed MFMA B-fragments. frag f = kc*32+nf (kc 0..15 = 32-wide
// k-chunk, nf 0..31 = 16-wide n-chunk); lane l holds n = nf*16+(l&15),
// k = kc*32+(l>>4)*8 .. +8 — 1KB/frag, lane-linear 16B loads.
__global__ __launch_bounds__(256) void k_prep(const float* __restrict__ W1, const float* __restrict__ W2,
                                              u16* __restrict__ W1x_t, u16* __restrict__ W1h_p,
                                              u16* __restrict__ W2_p) {
  int id = blockIdx.x * 256 + threadIdx.x;   // 98304
  int m = id >> 15;
  int r = id & 32767;
  if (m == 0) {
    int n = r >> 6, c = r & 63;
    const float* src = W1 + n;
    short8 pk;
#pragma unroll
    for (int j = 0; j < 8; ++j) pk[j] = (short)f2bf(src[(size_t)(c * 8 + j) * 512]);
    *(short8*)(W1x_t + (size_t)n * 512 + c * 8) = pk;
  } else {
    int f = r >> 6, l = r & 63;
    int kc = f >> 5, nf = f & 31;
    int n = (nf << 4) + (l & 15);
    int kb = (kc << 5) + ((l >> 4) << 3);
    const float* src = (m == 1) ? (W1 + (size_t)512 * 512) : W2;
    u16* dst = (m == 1) ? W1h_p : W2_p;
    short8 pk;
#pragma unroll
    for (int e = 0; e < 8; ++e) pk[e] = (short)f2bf(src[(size_t)(kb + e) * 512 + n]);
    *(short8*)(dst + ((size_t)f << 9) + (l << 3)) = pk;
  }
}

// ---------- X pre-convert: f32 -> bf16 once (memory-bound pass) ----------
__global__ __launch_bounds__(256) void k_cvtX(const float* __restrict__ X, u16* __restrict__ Xb) {
  size_t id = ((size_t)blockIdx.x * 256 + threadIdx.x) * 8;
  float4 f0 = *(const float4*)(X + id);
  float4 f1 = *(const float4*)(X + id + 4);
  short8 pk;
  pk[0] = (short)f2bf(f0.x); pk[1] = (short)f2bf(f0.y);
  pk[2] = (short)f2bf(f0.z); pk[3] = (short)f2bf(f0.w);
  pk[4] = (short)f2bf(f1.x); pk[5] = (short)f2bf(f1.y);
  pk[6] = (short)f2bf(f1.z); pk[7] = (short)f2bf(f1.w);
  *(short8*)(Xb + id) = pk;
}

// ---------- Phase A: U = bf16(Xb @ W1x + b1)   (M=65536, N=512, K=512) ----------
// Both operands bf16 via global_load_lds (m97 structure).
__global__ __launch_bounds__(256, 2) void k_phaseA(const u16* __restrict__ Xb,
                                                   const u16* __restrict__ Bt,
                                                   const float* __restrict__ b1,
                                                   u16* __restrict__ Ub) {
  int flat = blockIdx.x;
  int v = ((flat & 7) << 8) + (flat >> 3);   // XCD-chunked, bijective (2048 % 8 == 0)
  const int mt = v >> 2, nt = v & 3;
  const int tid = threadIdx.x;
  const int lane = tid & 63, wv = tid >> 6;
  const int wm = wv >> 1, wn = wv & 1;
  const int l15 = lane & 15, lg = lane >> 4;
  __shared__ __align__(16) u16 As[128 * 64];
  __shared__ __align__(16) u16 Bs[128 * 64];
  floatx4 acc[4][4];
  const floatx4 z4 = {0.f, 0.f, 0.f, 0.f};
#pragma unroll
  for (int i = 0; i < 4; ++i)
#pragma unroll
    for (int j = 0; j < 4; ++j) acc[i][j] = z4;

  const u16* Ab = Xb + (size_t)(mt * 128) * 512;
  const u16* Bb = Bt + (size_t)(nt * 128) * 512;

  for (int kt = 0; kt < 8; ++kt) {
    stage_swz<1024, 256, 3>(Ab + kt * 64, 512, As, tid);
    stage_swz<1024, 256, 3>(Bb + kt * 64, 512, Bs, tid);
    __syncthreads();
#pragma unroll
    for (int ks = 0; ks < 2; ++ks) {
      int kc = ks * 4 + lg;
      short8 a[4], b[4];
#pragma unroll
      for (int i = 0; i < 4; ++i) a[i] = frag_swz(As, wm * 64 + i * 16 + l15, kc);
#pragma unroll
      for (int i = 0; i < 4; ++i) b[i] = frag_swz(Bs, wn * 64 + i * 16 + l15, kc);
#pragma unroll
      for (int mi = 0; mi < 4; ++mi)
#pragma unroll
        for (int ni = 0; ni < 4; ++ni) acc[mi][ni] = mfma16(a[mi], b[ni], acc[mi][ni]);
    }
    __syncthreads();
  }
  const int r0 = mt * 128 + wm * 64, c0 = nt * 128 + wn * 64;
#pragma unroll
  for (int ni = 0; ni < 4; ++ni) {
    int col = c0 + ni * 16 + l15;
    float bb = b1[col];
#pragma unroll
    for (int mi = 0; mi < 4; ++mi)
#pragma unroll
      for (int j = 0; j < 4; ++j) {
        int row = r0 + mi * 16 + lg * 4 + j;
        Ub[(size_t)row * 512 + col] = f2bf(acc[mi][ni][j] + bb);
      }
  }
}

// ---------- Phase B: whole 32-step recurrence in ONE kernel ----------
// 128 blocks x 16 rows; state in LDS (chunk-XOR swizzled) for all 32 steps.
// waves_per_eu(2,2) pins 2 waves/EU -> 256-VGPR budget (round-7 counter showed
// the compiler capped at 128 and demoted breg to scratch: FETCH/WRITE each
// ~40MB over ideal, MfmaUtil 2.6%). Persistent W1h kc=0..7 = 128 VGPR exactly;
// kc=8..15 streamed via 3-deep static rotation in a separate fully-unrolled
// loop (all indices compile-time, rule #20). H stores issued AFTER the state
// barrier so their vmcnt drain hides under the next step's K-loop.
__global__ __launch_bounds__(512) __attribute__((amdgpu_waves_per_eu(2, 2)))
void k_stepseq(const float* __restrict__ pre,
               const u16* __restrict__ Ub,
               const u16* __restrict__ W1h_p,
               u16* __restrict__ H,
               float* __restrict__ Fs) {
  const int mt = blockIdx.x;          // 128 blocks x 16 rows
  const int r0 = mt * 16;
  const int tid = threadIdx.x;
  const int lane = tid & 63, wn = tid >> 6;      // 8 waves, wave tile 16m x 64n
  const int l15 = lane & 15, lg = lane >> 4;
  __shared__ __align__(16) u16 Ah[16 * 512];     // state, swizzled chunks
  __shared__ __align__(16) u16 Us[16 * 512];     // U_t tile, swizzled chunks

  // stage pre_state -> Ah (f32 load, bf16 convert, swizzled write)
  const float* Sp = pre + ((size_t)r0 << 9);
#pragma unroll
  for (int s0 = 0; s0 < 1024; s0 += 512) {
    int s = s0 + tid;
    int r = s >> 6, c = s & 63;
    const float* sp = Sp + ((size_t)r << 9) + (c << 3);
    float4 f0 = *(const float4*)sp;
    float4 f1 = *(const float4*)(sp + 4);
    short8 pk;
    pk[0] = (short)f2bf(f0.x); pk[1] = (short)f2bf(f0.y);
    pk[2] = (short)f2bf(f0.z); pk[3] = (short)f2bf(f0.w);
    pk[4] = (short)f2bf(f1.x); pk[5] = (short)f2bf(f1.y);
    pk[6] = (short)f2bf(f1.z); pk[7] = (short)f2bf(f1.w);
    *(short8*)(Ah + (r << 9) + ((c ^ (r & 7)) << 3)) = pk;
  }

  // persistent half of W1h: frag f = kc*32 + wn*4 + i, this lane's 16B
  const u16* Wb = W1h_p + ((size_t)(wn * 4) << 9) + (lane << 3);
  short8 breg[8][4];
#pragma unroll
  for (int kc = 0; kc < 8; ++kc)
#pragma unroll
    for (int i = 0; i < 4; ++i)
      breg[kc][i] = *(const short8*)(Wb + ((size_t)(kc * 32 + i) << 9));

  __syncthreads();
  const floatx4 z4 = {0.f, 0.f, 0.f, 0.f};

  for (int t = 0; t < 32; ++t) {
    // U_t -> LDS ([16][512] tile, 64 chunks/row; completes by barrier B1)
    stage_swz<1024, 512, 6>(Ub + ((size_t)t << 20) + ((size_t)r0 << 9), 512, Us, tid);

    // streamed half: 3-deep prefetch of groups 8,9,10
    short8 sb[3][4];
#pragma unroll
    for (int d = 0; d < 3; ++d)
#pragma unroll
      for (int i = 0; i < 4; ++i)
        sb[d][i] = *(const short8*)(Wb + ((size_t)((8 + d) * 32 + i) << 9));

    floatx4 acc[4] = {z4, z4, z4, z4};
    // ---- persistent K (kc 0..7): pure register + LDS, covers sb latency ----
#pragma unroll
    for (int kc = 0; kc < 8; ++kc) {
      short8 a = *(const short8*)(Ah + (l15 << 9) + ((((kc << 2) + lg) ^ (l15 & 7)) << 3));
      __builtin_amdgcn_s_setprio(1);
      acc[0] = mfma16(a, breg[kc][0], acc[0]);
      acc[1] = mfma16(a, breg[kc][1], acc[1]);
      acc[2] = mfma16(a, breg[kc][2], acc[2]);
      acc[3] = mfma16(a, breg[kc][3], acc[3]);
      __builtin_amdgcn_s_setprio(0);
    }
    // ---- streamed K (kc 8..15): 3-deep rotation, fully unrolled ----
#pragma unroll
    for (int kc = 8; kc < 16; ++kc) {
      const int d = (kc - 8) % 3;
      short8 c0 = sb[d][0], c1 = sb[d][1], c2 = sb[d][2], c3 = sb[d][3];
      if (kc + 3 < 16) {
#pragma unroll
        for (int i = 0; i < 4; ++i)
          sb[d][i] = *(const short8*)(Wb + ((size_t)((kc + 3) * 32 + i) << 9));
      }
      short8 a = *(const short8*)(Ah + (l15 << 9) + ((((kc << 2) + lg) ^ (l15 & 7)) << 3));
      __builtin_amdgcn_s_setprio(1);
      acc[0] = mfma16(a, c0, acc[0]);
      acc[1] = mfma16(a, c1, acc[1]);
      acc[2] = mfma16(a, c2, acc[2]);
      acc[3] = mfma16(a, c3, acc[3]);
      __builtin_amdgcn_s_setprio(0);
    }
    __syncthreads();   // B1: Ah reads done; Us staged; prev-step H stores drained

    // epilogue: compute h, update LDS state; keep hb in regs for post-B2 store
    u16 hb[16];
#pragma unroll
    for (int ni = 0; ni < 4; ++ni)
#pragma unroll
      for (int j = 0; j < 4; ++j) {
        int row = lg * 4 + j;
        int col = wn * 64 + ni * 16 + l15;
        int ch = col >> 3;
        float uvv = bf2f(Us[(row << 9) + ((ch ^ (row & 7)) << 3) + (col & 7)]);
        float hv = tanh_fast(acc[ni][j] + uvv);
        u16 h16 = f2bf(hv);
        hb[ni * 4 + j] = h16;
        Ah[(row << 9) + ((ch ^ (row & 7)) << 3) + (col & 7)] = h16;
      }
    __syncthreads();   // B2: state coherent for next step

    // H (+Fs at t=31) stores AFTER the barrier: drain overlaps next K-loop
    u16* Ht = H + ((size_t)t << 20) + ((size_t)r0 << 9);
#pragma unroll
    for (int ni = 0; ni < 4; ++ni)
#pragma unroll
      for (int j = 0; j < 4; ++j) {
        int row = lg * 4 + j;
        int col = wn * 64 + ni * 16 + l15;
        u16 h16 = hb[ni * 4 + j];
        Ht[(size_t)row * 512 + col] = h16;
        if (t == 31) Fs[(size_t)(r0 + row) * 512 + col] = bf2f(h16);
      }
  }
}

// ---------- Phase C: out = softmax(H @ W2 + b2)  (M=65536, full N=512/block) ----------
// B-operand straight from packed W2_p frags (register path, no LDS staging);
// only H goes through LDS. Online single-barrier softmax.
__global__ __launch_bounds__(512, 2) void k_phaseC(const u16* __restrict__ H,
                                                   const u16* __restrict__ W2_p,
                                                   const float* __restrict__ b2,
                                                   float* __restrict__ Out) {
  int bt = ((blockIdx.x & 7) << 7) + (blockIdx.x >> 3);   // XCD-chunked (1024 % 8 == 0)
  const int tid = threadIdx.x, lane = tid & 63, wv = tid >> 6;
  const int wm = wv >> 2, wn = wv & 3;
  const int l15 = lane & 15, lg = lane >> 4;
  __shared__ __align__(16) u16 As[64 * 64];
  __shared__ float redmax[4][64];
  __shared__ float redsum[4][64];
  const floatx4 z4 = {0.f, 0.f, 0.f, 0.f};
  floatx4 acc[2][8];
#pragma unroll
  for (int i = 0; i < 2; ++i)
#pragma unroll
    for (int j = 0; j < 8; ++j) acc[i][j] = z4;

  const u16* Ab = H + (size_t)(bt * 64) * 512;
  const u16* Wb = W2_p + ((size_t)(wn * 8) << 9) + (lane << 3);  // nf base = wn*8

  for (int kt = 0; kt < 8; ++kt) {
    stage_swz<512, 512, 3>(Ab + kt * 64, 512, As, tid);
    __syncthreads();
#pragma unroll
    for (int ks = 0; ks < 2; ++ks) {
      int kc = ks * 4 + lg;          // LDS 8-elem chunk index for A
      int kcg = kt * 2 + ks;         // global 32-wide k-chunk for B frags
      short8 a[2], b[8];
#pragma unroll
      for (int i = 0; i < 2; ++i) a[i] = frag_swz(As, wm * 32 + i * 16 + l15, kc);
#pragma unroll
      for (int i = 0; i < 8; ++i) b[i] = *(const short8*)(Wb + ((size_t)(kcg * 32 + i) << 9));
#pragma unroll
      for (int mi = 0; mi < 2; ++mi)
#pragma unroll
        for (int ni = 0; ni < 8; ++ni) acc[mi][ni] = mfma16(a[mi], b[ni], acc[mi][ni]);
    }
    __syncthreads();
  }
  // logits = acc + b2; per-wave online softmax stats
  float v[2][8][4];
#pragma unroll
  for (int ni = 0; ni < 8; ++ni) {
    float bb = b2[wn * 128 + ni * 16 + l15];
#pragma unroll
    for (int mi = 0; mi < 2; ++mi)
#pragma unroll
      for (int j = 0; j < 4; ++j) v[mi][ni][j] = acc[mi][ni][j] + bb;
  }
  float mw[2][4];
#pragma unroll
  for (int mi = 0; mi < 2; ++mi)
#pragma unroll
    for (int j = 0; j < 4; ++j) {
      float m = v[mi][0][j];
#pragma unroll
      for (int ni = 1; ni < 8; ++ni) m = fmaxf(m, v[mi][ni][j]);
#pragma unroll
      for (int d = 1; d < 16; d <<= 1) m = fmaxf(m, __shfl_xor(m, d, 64));
      mw[mi][j] = m;
      float s = 0.f;
#pragma unroll
      for (int ni = 0; ni < 8; ++ni) {
        v[mi][ni][j] = __expf(v[mi][ni][j] - m);   // p = exp(v - m_w)
        s += v[mi][ni][j];
      }
#pragma unroll
      for (int d = 1; d < 16; d <<= 1) s += __shfl_xor(s, d, 64);
      if (l15 == 0) {
        int row = wm * 32 + mi * 16 + lg * 4 + j;
        redmax[wn][row] = m;
        redsum[wn][row] = s;
      }
    }
  __syncthreads();
#pragma unroll
  for (int mi = 0; mi < 2; ++mi)
#pragma unroll
    for (int j = 0; j < 4; ++j) {
      int row = wm * 32 + mi * 16 + lg * 4 + j;
      float m0 = redmax[0][row], m1 = redmax[1][row], m2 = redmax[2][row], m3 = redmax[3][row];
      float M = fmaxf(fmaxf(m0, m1), fmaxf(m2, m3));
      float S = redsum[0][row] * __expf(m0 - M) + redsum[1][row] * __expf(m1 - M) +
                redsum[2][row] * __expf(m2 - M) + redsum[3][row] * __expf(m3 - M);
      float scale = __expf(mw[mi][j] - M) / S;
#pragma unroll
      for (int ni = 0; ni < 8; ++ni)
        Out[(size_t)(bt * 64 + row) * 512 + wn * 128 + ni * 16 + l15] = v[mi][ni][j] * scale;
    }
}

// ---------- host ----------
extern "C" void kernel_launch(void* const* d_in, const int* in_sizes, int n_in,
                              void* d_out, int out_size, void* d_ws, size_t ws_size,
                              hipStream_t stream) {
  const float* input = (const float*)d_in[0];       // (32, 2048, 512)
  const float* pre_state = (const float*)d_in[1];   // (2048, 512)
  const float* W1 = (const float*)d_in[2];          // (1024, 512)
  const float* b1 = (const float*)d_in[3];          // (512,)
  const float* W2 = (const float*)d_in[4];          // (512, 512)
  const float* b2 = (const float*)d_in[5];          // (512,)

  float* out = (float*)d_out;                        // probs (33.5M f32) then final_state (1M f32)
  float* final_state = out + (size_t)32 * 2048 * 512;
  // d_out scratch aliasing (all dead before the overwriting phase):
  //   bytes [0,   64M): Ub  (bf16 U) — written phaseA, read stepseq, overwritten phaseC
  //   bytes [64M, 128M): Xb  (bf16 X) — written cvtX, read phaseA, overwritten phaseC
  u16* Ub = (u16*)d_out;
  u16* Xb = (u16*)d_out + (size_t)32 * 2048 * 512;

  u16* ws16 = (u16*)d_ws;                            // total ws use: ~66 MB
  u16* W1x_t = ws16;                                 // [512][512] bf16
  u16* W1h_p = W1x_t + 262144;                       // packed frags, 512 KB
  u16* W2_p  = W1h_p + 262144;                       // packed frags, 512 KB
  u16* H     = W2_p + 262144;                        // [32][2048][512] bf16, 64 MB

  k_prep<<<384, 256, 0, stream>>>(W1, W2, W1x_t, W1h_p, W2_p);
  k_cvtX<<<16384, 256, 0, stream>>>(input, Xb);
  k_phaseA<<<2048, 256, 0, stream>>>(Xb, W1x_t, b1, Ub);
  k_stepseq<<<128, 512, 0, stream>>>(pre_state, Ub, W1h_p, H, final_state);
  k_phaseC<<<1024, 512, 0, stream>>>(H, W2_p, b2, out);
}